// Round 12
// baseline (315.021 us; speedup 1.0000x reference)
//
#include <hip/hip_runtime.h>

// GATPool: 3-layer GAT (N=20480, E=327680, H=4, D=64) + mean pool + classifier.
// R12: producer/consumer fusion — attn_i + gemm_{i+1} in one 512-thread kernel
// (attn stages h-tile in XOR-swizzled LDS; gemm reads A from LDS). 7 dispatches.

#define NNODES 20480
#define NEDGES 327680
#define NGRAPH 64
#define NPG    320        // nodes per graph
#define HD     256        // H*D
#define NH     4
#define NCLS   10
#define SLOTS  80         // max in-degree slack (true max ~40, P(>64)~1e-19)

typedef __attribute__((ext_vector_type(8))) short short8;
typedef __attribute__((ext_vector_type(8))) unsigned short ushort8v;
typedef __attribute__((ext_vector_type(4))) float f32x4;

__device__ __forceinline__ float elu_f(float x)   { return x > 0.f ? x : expm1f(x); }
__device__ __forceinline__ float lrelu_f(float x) { return x > 0.f ? x : 0.2f * x; }

__device__ __forceinline__ ushort f2bf(float v) {
    uint u = __float_as_uint(v);
    uint r = (u + 0x7fffu + ((u >> 16) & 1u)) >> 16;
    return (ushort)r;
}
__device__ __forceinline__ float bf2f(ushort u) {
    return __uint_as_float(((uint)u) << 16);
}

// truncation split of 8 consecutive f32 -> bf16 hi/lo fragments.
__device__ __forceinline__ void split8(const float* __restrict__ p,
                                       short8& hi, short8& lo) {
    float4 a = *reinterpret_cast<const float4*>(p);
    float4 b = *reinterpret_cast<const float4*>(p + 4);
    float v[8] = {a.x, a.y, a.z, a.w, b.x, b.y, b.z, b.w};
    #pragma unroll
    for (int e = 0; e < 8; e++) {
        uint u = __float_as_uint(v[e]);
        hi[e] = (short)(u >> 16);
        float hf = __uint_as_float(u & 0xFFFF0000u);
        float lf = v[e] - hf;                      // exact
        lo[e] = (short)(__float_as_uint(lf) >> 16);
    }
}

// Combined prep: blocks [0,1280) fill adjacency slots; rest split W0/W1/W2
// into bf16 hi/lo fragment panels.
__global__ __launch_bounds__(256) void prep_k(
        const int* __restrict__ src, const int* __restrict__ dst,
        int* __restrict__ deg, int* __restrict__ slots,
        const float* __restrict__ W0, ushort* __restrict__ B0h, ushort* __restrict__ B0l,
        const float* __restrict__ W1, ushort* __restrict__ B1h, ushort* __restrict__ B1l,
        const float* __restrict__ W2, ushort* __restrict__ B2h, ushort* __restrict__ B2l) {
    int b = blockIdx.x;
    if (b < NEDGES / 256) {
        int e = b * 256 + threadIdx.x;
        int d = dst[e];
        int pos = atomicAdd(&deg[d], 1);
        if (pos < SLOTS) slots[d * SLOTS + pos] = src[e];
    } else {
        int idx = (b - NEDGES / 256) * 256 + threadIdx.x;
        const float* W; ushort *Bh, *Bl;
        if (idx < 128 * 256)          { W = W0; Bh = B0h; Bl = B0l; }
        else if (idx < 384 * 256)     { W = W1; Bh = B1h; Bl = B1l; idx -= 128 * 256; }
        else                          { W = W2; Bh = B2h; Bl = B2l; idx -= 384 * 256; }
        int k = idx >> 8, col = idx & 255;
        float v = W[idx];
        ushort h = f2bf(v);
        float vh = bf2f(h);
        ushort l = f2bf(v - vh);
        size_t o = (size_t)(k >> 5) * 8192 + (size_t)col * 32 + (k & 31);
        Bh[o] = h;
        Bl[o] = l;
    }
}

// Standalone layer-0 GEMM: z = x*W0 via split-bf16 3-pass MFMA (A f32,
// in-register split). Writes bf16 z + fused el/er epilogue.
__global__ __launch_bounds__(256) void gemm0_k(
        const float* __restrict__ A,
        const ushort* __restrict__ Bhi, const ushort* __restrict__ Blo,
        const float* __restrict__ al_, const float* __restrict__ ar_,
        ushort* __restrict__ zbf, float* __restrict__ el, float* __restrict__ er) {
    const int K = 128;
    int m0 = blockIdx.x * 32;
    int w = threadIdx.x >> 6, l = threadIdx.x & 63;
    int n0 = w * 64;
    int lr = l & 15, lk = l >> 4;
    f32x4 acc[2][4] = {};
    #pragma unroll
    for (int kt = 0; kt < K / 32; kt++) {
        int kbase = kt * 32 + lk * 8;
        short8 a_hi[2], a_lo[2], b_hi[4], b_lo[4];
        #pragma unroll
        for (int i = 0; i < 2; i++) {
            size_t off = (size_t)(m0 + i * 16 + lr) * K + kbase;
            split8(A + off, a_hi[i], a_lo[i]);
        }
        #pragma unroll
        for (int j = 0; j < 4; j++) {
            size_t off = (size_t)kt * 8192 + (size_t)(n0 + j * 16 + lr) * 32 + lk * 8;
            b_hi[j] = *reinterpret_cast<const short8*>(Bhi + off);
            b_lo[j] = *reinterpret_cast<const short8*>(Blo + off);
        }
        #pragma unroll
        for (int i = 0; i < 2; i++)
            #pragma unroll
            for (int j = 0; j < 4; j++) {
                acc[i][j] = __builtin_amdgcn_mfma_f32_16x16x32_bf16(a_hi[i], b_hi[j], acc[i][j], 0, 0, 0);
                acc[i][j] = __builtin_amdgcn_mfma_f32_16x16x32_bf16(a_hi[i], b_lo[j], acc[i][j], 0, 0, 0);
                acc[i][j] = __builtin_amdgcn_mfma_f32_16x16x32_bf16(a_lo[i], b_hi[j], acc[i][j], 0, 0, 0);
            }
    }
    float alv[4], arv[4];
    #pragma unroll
    for (int j = 0; j < 4; j++) {
        int col = n0 + j * 16 + lr;
        alv[j] = al_[col];
        arv[j] = ar_[col];
    }
    #pragma unroll
    for (int i = 0; i < 2; i++) {
        #pragma unroll
        for (int r = 0; r < 4; r++) {
            float pel = 0.f, per = 0.f;
            #pragma unroll
            for (int j = 0; j < 4; j++) {
                float v = acc[i][j][r];
                pel += v * alv[j];
                per += v * arv[j];
                int row = m0 + i * 16 + lk * 4 + r;
                int col = n0 + j * 16 + lr;
                zbf[(size_t)row * HD + col] = f2bf(v);
            }
            #pragma unroll
            for (int off = 1; off < 16; off <<= 1) {
                pel += __shfl_xor(pel, off);
                per += __shfl_xor(per, off);
            }
            if (lr == 0) {
                int row = m0 + i * 16 + lk * 4 + r;
                el[row * NH + w] = pel;
                er[row * NH + w] = per;
            }
        }
    }
}

// Standalone attn (layer 2 output): as R11. Wave per node.
__global__ __launch_bounds__(256) void attn_aggr_k(
        const ushort* __restrict__ zbf,
        const float* __restrict__ el, const float* __restrict__ er,
        const int* __restrict__ deg, const int* __restrict__ slots,
        const ushort* __restrict__ hin, ushort* __restrict__ hout,
        int residual) {
    int wid = threadIdx.x >> 6, lane = threadIdx.x & 63;
    int n = blockIdx.x * 4 + wid;
    int h = lane >> 4, j16 = lane & 15;
    int l32 = lane & 31, half = lane >> 5;
    int headL = l32 >> 3;
    int col8 = l32 * 8;
    int d = deg[n];
    if (d > SLOTS) d = SLOTS;
    const int* sl = slots + (size_t)n * SLOTS;
    float ern = er[n * NH + h];
    float acc[8] = {};

    if (d <= 64) {
        float pv[4];
        int   sv[4];
        #pragma unroll
        for (int u = 0; u < 4; u++) {
            int k = u * 16 + j16;
            if (k < d) {
                sv[u] = sl[k];
                pv[u] = __expf(lrelu_f(el[sv[u] * NH + h] + ern));
            } else {
                sv[u] = 0;
                pv[u] = 0.f;
            }
        }
        float ssum = pv[0] + pv[1] + pv[2] + pv[3];
        #pragma unroll
        for (int off = 1; off < 16; off <<= 1) ssum += __shfl_xor(ssum, off);
        float rinv = 1.f / ssum;
        #pragma unroll
        for (int u = 0; u < 4; u++) pv[u] *= rinv;
        #pragma unroll
        for (int u = 0; u < 4; u++) {
            if (u * 16 >= d) break;
            #pragma unroll
            for (int jj = 0; jj < 8; jj++) {
                int e = u * 16 + jj * 2 + half;
                int srcl = headL * 16 + jj * 2 + half;
                float w = __shfl(pv[u], srcl);
                int   s = __shfl(sv[u], srcl);
                if (e < d) {
                    ushort8v zv = *reinterpret_cast<const ushort8v*>(&zbf[(size_t)s * HD + col8]);
                    #pragma unroll
                    for (int t = 0; t < 8; t++) acc[t] += bf2f(zv[t]) * w;
                }
            }
        }
        #pragma unroll
        for (int t = 0; t < 8; t++) acc[t] += __shfl_xor(acc[t], 32);
    } else {
        float ssum = 0.f;
        for (int k = j16; k < d; k += 16)
            ssum += __expf(lrelu_f(el[sl[k] * NH + h] + ern));
        #pragma unroll
        for (int off = 1; off < 16; off <<= 1) ssum += __shfl_xor(ssum, off);
        float rinv = 1.f / ssum;
        float rinvL = __shfl(rinv, headL * 16);
        float ernL = er[n * NH + headL];
        for (int k = 0; k < d; k++) {
            int s = sl[k];
            float w = __expf(lrelu_f(el[s * NH + headL] + ernL)) * rinvL;
            ushort8v zv = *reinterpret_cast<const ushort8v*>(&zbf[(size_t)s * HD + col8]);
            #pragma unroll
            for (int t = 0; t < 8; t++) acc[t] += bf2f(zv[t]) * w;
        }
    }

    if (half == 0) {
        size_t o = (size_t)n * HD + col8;
        ushort8v r;
        if (residual) {
            ushort8v hv = *reinterpret_cast<const ushort8v*>(&hin[o]);
            #pragma unroll
            for (int t = 0; t < 8; t++)
                r[t] = f2bf(elu_f(elu_f(acc[t] + bf2f(hv[t]))));
        } else {
            #pragma unroll
            for (int t = 0; t < 8; t++)
                r[t] = f2bf(elu_f(acc[t]));
        }
        *reinterpret_cast<ushort8v*>(&hout[o]) = r;
    }
}

// Fused attn_i (wave-per-node, 4 nodes per wave sequentially) + gemm_{i+1}
// (A = h tile from XOR-swizzled LDS, 2-pass bf16 MFMA, K=256).
// 512 threads = 8 waves; block owns nodes/rows [m0, m0+32).
template<int RES>
__global__ __launch_bounds__(512) void attn_gemm_k(
        const ushort* __restrict__ zin,
        const float* __restrict__ eli, const float* __restrict__ eri,
        const int* __restrict__ deg, const int* __restrict__ slots,
        ushort* __restrict__ hbuf,      // residual in (RES=1) / h_{i+1} out
        const ushort* __restrict__ Bhi, const ushort* __restrict__ Blo,
        const float* __restrict__ al_, const float* __restrict__ ar_,
        ushort* __restrict__ zout, float* __restrict__ elo, float* __restrict__ ero) {
    __shared__ ushort hts[32 * 256];   // 16 KB, 16B-chunk XOR-swizzled by row&7
    int m0 = blockIdx.x * 32;
    int wv = threadIdx.x >> 6, lane = threadIdx.x & 63;
    int h = lane >> 4, j16 = lane & 15;
    int l32 = lane & 31, half = lane >> 5;
    int headL = l32 >> 3;
    int col8 = l32 * 8;

    // ---- attn phase: 4 nodes per wave ----
    for (int q = 0; q < 4; q++) {
        int rloc = wv * 4 + q;
        int n = m0 + rloc;
        int d = deg[n];
        if (d > SLOTS) d = SLOTS;
        const int* sl = slots + (size_t)n * SLOTS;
        float ern = eri[n * NH + h];
        float acc[8] = {};

        if (d <= 64) {
            float pv[4];
            int   sv[4];
            #pragma unroll
            for (int u = 0; u < 4; u++) {
                int k = u * 16 + j16;
                if (k < d) {
                    sv[u] = sl[k];
                    pv[u] = __expf(lrelu_f(eli[sv[u] * NH + h] + ern));
                } else {
                    sv[u] = 0;
                    pv[u] = 0.f;
                }
            }
            float ssum = pv[0] + pv[1] + pv[2] + pv[3];
            #pragma unroll
            for (int off = 1; off < 16; off <<= 1) ssum += __shfl_xor(ssum, off);
            float rinv = 1.f / ssum;
            #pragma unroll
            for (int u = 0; u < 4; u++) pv[u] *= rinv;
            #pragma unroll
            for (int u = 0; u < 4; u++) {
                if (u * 16 >= d) break;
                #pragma unroll
                for (int jj = 0; jj < 8; jj++) {
                    int e = u * 16 + jj * 2 + half;
                    int srcl = headL * 16 + jj * 2 + half;
                    float w = __shfl(pv[u], srcl);
                    int   s = __shfl(sv[u], srcl);
                    if (e < d) {
                        ushort8v zv = *reinterpret_cast<const ushort8v*>(&zin[(size_t)s * HD + col8]);
                        #pragma unroll
                        for (int t = 0; t < 8; t++) acc[t] += bf2f(zv[t]) * w;
                    }
                }
            }
            #pragma unroll
            for (int t = 0; t < 8; t++) acc[t] += __shfl_xor(acc[t], 32);
        } else {
            float ssum = 0.f;
            for (int k = j16; k < d; k += 16)
                ssum += __expf(lrelu_f(eli[sl[k] * NH + h] + ern));
            #pragma unroll
            for (int off = 1; off < 16; off <<= 1) ssum += __shfl_xor(ssum, off);
            float rinv = 1.f / ssum;
            float rinvL = __shfl(rinv, headL * 16);
            float ernL = eri[n * NH + headL];
            for (int k = 0; k < d; k++) {
                int s = sl[k];
                float w = __expf(lrelu_f(eli[s * NH + headL] + ernL)) * rinvL;
                ushort8v zv = *reinterpret_cast<const ushort8v*>(&zin[(size_t)s * HD + col8]);
                #pragma unroll
                for (int t = 0; t < 8; t++) acc[t] += bf2f(zv[t]) * w;
            }
        }

        if (half == 0) {
            size_t o = (size_t)n * HD + col8;
            ushort8v r;
            if (RES) {
                ushort8v hv = *reinterpret_cast<const ushort8v*>(&hbuf[o]);
                #pragma unroll
                for (int t = 0; t < 8; t++)
                    r[t] = f2bf(elu_f(elu_f(acc[t] + bf2f(hv[t]))));
            } else {
                #pragma unroll
                for (int t = 0; t < 8; t++)
                    r[t] = f2bf(elu_f(acc[t]));
            }
            *reinterpret_cast<ushort8v*>(&hbuf[o]) = r;
            // swizzled LDS stage: 16B chunk index = l32 ^ (row&7)
            *reinterpret_cast<ushort8v*>(&hts[rloc * 256 + (col8 ^ ((rloc & 7) << 3))]) = r;
        }
    }
    __syncthreads();

    // ---- gemm phase: z_{i+1}[m0..m0+32) = h_tile * W, 2-pass bf16 ----
    int wr = wv >> 2, wc = wv & 3;    // 2 row-groups x 4 heads
    int n0 = wc * 64;
    int lr = lane & 15, lk = lane >> 4;
    f32x4 gacc[4] = {};
    #pragma unroll
    for (int kt = 0; kt < 8; kt++) {
        int arow = wr * 16 + lr;
        short8 a = *reinterpret_cast<const short8*>(
            &hts[arow * 256 + ((((kt * 4 + lk) ^ (arow & 7)) << 3))]);
        #pragma unroll
        for (int j = 0; j < 4; j++) {
            size_t off = (size_t)kt * 8192 + (size_t)(n0 + j * 16 + lr) * 32 + lk * 8;
            short8 bh = *reinterpret_cast<const short8*>(Bhi + off);
            short8 bl = *reinterpret_cast<const short8*>(Blo + off);
            gacc[j] = __builtin_amdgcn_mfma_f32_16x16x32_bf16(a, bh, gacc[j], 0, 0, 0);
            gacc[j] = __builtin_amdgcn_mfma_f32_16x16x32_bf16(a, bl, gacc[j], 0, 0, 0);
        }
    }
    float alv[4], arv[4];
    #pragma unroll
    for (int j = 0; j < 4; j++) {
        int col = n0 + j * 16 + lr;
        alv[j] = al_[col];
        arv[j] = ar_[col];
    }
    #pragma unroll
    for (int r = 0; r < 4; r++) {
        float pel = 0.f, per = 0.f;
        #pragma unroll
        for (int j = 0; j < 4; j++) {
            float v = gacc[j][r];
            pel += v * alv[j];
            per += v * arv[j];
            int row = m0 + wr * 16 + lk * 4 + r;
            int col = n0 + j * 16 + lr;
            zout[(size_t)row * HD + col] = f2bf(v);
        }
        #pragma unroll
        for (int off = 1; off < 16; off <<= 1) {
            pel += __shfl_xor(pel, off);
            per += __shfl_xor(per, off);
        }
        if (lr == 0) {
            int row = m0 + wr * 16 + lk * 4 + r;
            elo[row * NH + wc] = pel;
            ero[row * NH + wc] = per;
        }
    }
}

// per-graph mean (4-way node split over 1024 threads) + elu + classifier.
__global__ __launch_bounds__(1024) void poolcls_k(const ushort* __restrict__ h,
                                                  const float* __restrict__ Wc,
                                                  const float* __restrict__ bc,
                                                  float* __restrict__ out) {
    __shared__ float part[4][HD];
    __shared__ float hv[HD];
    int g = blockIdx.x, t = threadIdx.x;
    int col = t & 255, q = t >> 8;               // quarter 0..3
    const ushort* p = h + (size_t)g * NPG * HD + (size_t)q * (NPG / 4) * HD + col;
    float s = 0.f;
    for (int i = 0; i < NPG / 4; i++) s += bf2f(p[(size_t)i * HD]);
    part[q][col] = s;
    __syncthreads();
    if (t < HD) {
        float tot = part[0][t] + part[1][t] + part[2][t] + part[3][t];
        hv[t] = elu_f(tot * (1.0f / NPG));
    }
    __syncthreads();
    if (t < NCLS) {
        float acc = bc[t];
        for (int k = 0; k < HD; k++) acc += hv[k] * Wc[k * NCLS + t];
        out[g * NCLS + t] = acc;
    }
}

extern "C" void kernel_launch(void* const* d_in, const int* in_sizes, int n_in,
                              void* d_out, int out_size, void* d_ws, size_t ws_size,
                              hipStream_t stream) {
    const float* x   = (const float*)d_in[0];
    const int*   src = (const int*)d_in[1];
    const int*   dst = (const int*)d_in[2];
    const float* W0  = (const float*)d_in[4];
    const float* al0 = (const float*)d_in[5];
    const float* ar0 = (const float*)d_in[6];
    const float* W1  = (const float*)d_in[7];
    const float* al1 = (const float*)d_in[8];
    const float* ar1 = (const float*)d_in[9];
    const float* W2  = (const float*)d_in[10];
    const float* al2 = (const float*)d_in[11];
    const float* ar2 = (const float*)d_in[12];
    const float* Wc  = (const float*)d_in[13];
    const float* bc  = (const float*)d_in[14];
    float* out = (float*)d_out;

    char* ws = (char*)d_ws;
    size_t off = 0;
    auto alloc = [&](size_t bytes) -> void* {
        void* p = ws + off;
        off = (off + bytes + 255) & ~(size_t)255;
        return p;
    };
    ushort* hbuf     = (ushort*)alloc((size_t)NNODES * HD * 2);
    ushort* zA       = (ushort*)alloc((size_t)NNODES * HD * 2);
    ushort* zB       = (ushort*)alloc((size_t)NNODES * HD * 2);
    float*  elA      = (float*)alloc((size_t)NNODES * NH * 4);
    float*  erA      = (float*)alloc((size_t)NNODES * NH * 4);
    float*  elB      = (float*)alloc((size_t)NNODES * NH * 4);
    float*  erB      = (float*)alloc((size_t)NNODES * NH * 4);
    int*    deg      = (int*)alloc((size_t)NNODES * 4);
    int*    slots    = (int*)alloc((size_t)NNODES * SLOTS * 4);
    ushort* B0h      = (ushort*)alloc((size_t)128 * 256 * 2);
    ushort* B0l      = (ushort*)alloc((size_t)128 * 256 * 2);
    ushort* B1h      = (ushort*)alloc((size_t)256 * 256 * 2);
    ushort* B1l      = (ushort*)alloc((size_t)256 * 256 * 2);
    ushort* B2h      = (ushort*)alloc((size_t)256 * 256 * 2);
    ushort* B2l      = (ushort*)alloc((size_t)256 * 256 * 2);

    // ---- adjacency (fixed-slot) + weight panels ----
    hipMemsetAsync(deg, 0, (size_t)NNODES * 4, stream);
    prep_k<<<NEDGES / 256 + (128 + 256 + 256), 256, 0, stream>>>(
        src, dst, deg, slots,
        W0, B0h, B0l, W1, B1h, B1l, W2, B2h, B2l);

    // layer 0 GEMM: z0 = x @ W0 (f32 A, 3-pass)
    gemm0_k<<<NNODES / 32, 256, 0, stream>>>(x, B0h, B0l, al0, ar0, zA, elA, erA);

    // attn0 + gemm1 (no residual in attn0)
    attn_gemm_k<0><<<NNODES / 32, 512, 0, stream>>>(
        zA, elA, erA, deg, slots, hbuf, B1h, B1l, al1, ar1, zB, elB, erB);

    // attn1 + gemm2 (residual)
    attn_gemm_k<1><<<NNODES / 32, 512, 0, stream>>>(
        zB, elB, erB, deg, slots, hbuf, B2h, B2l, al2, ar2, zA, elA, erA);

    // attn2 (residual) -> final h
    attn_aggr_k<<<NNODES / 4, 256, 0, stream>>>(zA, elA, erA, deg, slots,
                                                hbuf, hbuf, 1);

    poolcls_k<<<NGRAPH, 1024, 0, stream>>>(hbuf, Wc, bc, out);
}

// Round 13
// 275.135 us; speedup vs baseline: 1.1450x; 1.1450x over previous
//
#include <hip/hip_runtime.h>

// GATPool: 3-layer GAT (N=20480, E=327680, H=4, D=64) + mean pool + classifier.
// R13: revert R12 fusion (regressed: barrier-serialized attn + bank conflicts).
// R11 structure + phase-2 gather restructured into explicit shfl/load/fma
// passes (8 independent 16B loads in flight per lane).

#define NNODES 20480
#define NEDGES 327680
#define NGRAPH 64
#define NPG    320        // nodes per graph
#define HD     256        // H*D
#define NH     4
#define NCLS   10
#define SLOTS  80         // max in-degree slack (true max ~40, P(>64)~1e-19)

typedef __attribute__((ext_vector_type(8))) short short8;
typedef __attribute__((ext_vector_type(8))) unsigned short ushort8v;
typedef __attribute__((ext_vector_type(4))) float f32x4;

__device__ __forceinline__ float elu_f(float x)   { return x > 0.f ? x : expm1f(x); }
__device__ __forceinline__ float lrelu_f(float x) { return x > 0.f ? x : 0.2f * x; }

__device__ __forceinline__ ushort f2bf(float v) {
    uint u = __float_as_uint(v);
    uint r = (u + 0x7fffu + ((u >> 16) & 1u)) >> 16;
    return (ushort)r;
}
__device__ __forceinline__ float bf2f(ushort u) {
    return __uint_as_float(((uint)u) << 16);
}

// truncation split of 8 consecutive f32 -> bf16 hi/lo fragments.
__device__ __forceinline__ void split8(const float* __restrict__ p,
                                       short8& hi, short8& lo) {
    float4 a = *reinterpret_cast<const float4*>(p);
    float4 b = *reinterpret_cast<const float4*>(p + 4);
    float v[8] = {a.x, a.y, a.z, a.w, b.x, b.y, b.z, b.w};
    #pragma unroll
    for (int e = 0; e < 8; e++) {
        uint u = __float_as_uint(v[e]);
        hi[e] = (short)(u >> 16);
        float hf = __uint_as_float(u & 0xFFFF0000u);
        float lf = v[e] - hf;                      // exact
        lo[e] = (short)(__float_as_uint(lf) >> 16);
    }
}

// Combined prep: blocks [0,1280) fill adjacency slots; rest split W0/W1/W2
// into bf16 hi/lo fragment panels.
__global__ __launch_bounds__(256) void prep_k(
        const int* __restrict__ src, const int* __restrict__ dst,
        int* __restrict__ deg, int* __restrict__ slots,
        const float* __restrict__ W0, ushort* __restrict__ B0h, ushort* __restrict__ B0l,
        const float* __restrict__ W1, ushort* __restrict__ B1h, ushort* __restrict__ B1l,
        const float* __restrict__ W2, ushort* __restrict__ B2h, ushort* __restrict__ B2l) {
    int b = blockIdx.x;
    if (b < NEDGES / 256) {
        int e = b * 256 + threadIdx.x;
        int d = dst[e];
        int pos = atomicAdd(&deg[d], 1);
        if (pos < SLOTS) slots[d * SLOTS + pos] = src[e];
    } else {
        int idx = (b - NEDGES / 256) * 256 + threadIdx.x;
        const float* W; ushort *Bh, *Bl;
        if (idx < 128 * 256)          { W = W0; Bh = B0h; Bl = B0l; }
        else if (idx < 384 * 256)     { W = W1; Bh = B1h; Bl = B1l; idx -= 128 * 256; }
        else                          { W = W2; Bh = B2h; Bl = B2l; idx -= 384 * 256; }
        int k = idx >> 8, col = idx & 255;
        float v = W[idx];
        ushort h = f2bf(v);
        float vh = bf2f(h);
        ushort l = f2bf(v - vh);
        size_t o = (size_t)(k >> 5) * 8192 + (size_t)col * 32 + (k & 31);
        Bh[o] = h;
        Bl[o] = l;
    }
}

// z = A*B via split-bf16 MFMA. ABF16=0: A f32, in-register split, 3 passes.
// ABF16=1: A bf16 rows, 2 passes (a_lo==0). Writes bf16 z + fused el/er.
template<int ABF16>
__global__ __launch_bounds__(256) void gemm_mfma_k(
        const void* __restrict__ Av,
        const ushort* __restrict__ Bhi, const ushort* __restrict__ Blo,
        const float* __restrict__ al_, const float* __restrict__ ar_,
        ushort* __restrict__ zbf, float* __restrict__ el, float* __restrict__ er,
        int K) {
    int m0 = blockIdx.x * 32;
    int w = threadIdx.x >> 6, l = threadIdx.x & 63;
    int n0 = w * 64;
    int lr = l & 15, lk = l >> 4;
    f32x4 acc[2][4] = {};
    int ksteps = K >> 5;
    for (int kt = 0; kt < ksteps; kt++) {
        int kbase = kt * 32 + lk * 8;
        short8 a_hi[2], a_lo[2], b_hi[4], b_lo[4];
        #pragma unroll
        for (int i = 0; i < 2; i++) {
            size_t off = (size_t)(m0 + i * 16 + lr) * K + kbase;
            if (ABF16) {
                a_hi[i] = *reinterpret_cast<const short8*>((const ushort*)Av + off);
            } else {
                split8((const float*)Av + off, a_hi[i], a_lo[i]);
            }
        }
        #pragma unroll
        for (int j = 0; j < 4; j++) {
            size_t off = (size_t)kt * 8192 + (size_t)(n0 + j * 16 + lr) * 32 + lk * 8;
            b_hi[j] = *reinterpret_cast<const short8*>(Bhi + off);
            b_lo[j] = *reinterpret_cast<const short8*>(Blo + off);
        }
        #pragma unroll
        for (int i = 0; i < 2; i++)
            #pragma unroll
            for (int j = 0; j < 4; j++) {
                acc[i][j] = __builtin_amdgcn_mfma_f32_16x16x32_bf16(a_hi[i], b_hi[j], acc[i][j], 0, 0, 0);
                acc[i][j] = __builtin_amdgcn_mfma_f32_16x16x32_bf16(a_hi[i], b_lo[j], acc[i][j], 0, 0, 0);
                if (!ABF16)
                    acc[i][j] = __builtin_amdgcn_mfma_f32_16x16x32_bf16(a_lo[i], b_hi[j], acc[i][j], 0, 0, 0);
            }
    }
    float alv[4], arv[4];
    #pragma unroll
    for (int j = 0; j < 4; j++) {
        int col = n0 + j * 16 + lr;
        alv[j] = al_[col];
        arv[j] = ar_[col];
    }
    #pragma unroll
    for (int i = 0; i < 2; i++) {
        #pragma unroll
        for (int r = 0; r < 4; r++) {
            float pel = 0.f, per = 0.f;
            #pragma unroll
            for (int j = 0; j < 4; j++) {
                float v = acc[i][j][r];
                pel += v * alv[j];
                per += v * arv[j];
                int row = m0 + i * 16 + lk * 4 + r;
                int col = n0 + j * 16 + lr;
                zbf[(size_t)row * HD + col] = f2bf(v);
            }
            #pragma unroll
            for (int off = 1; off < 16; off <<= 1) {
                pel += __shfl_xor(pel, off);
                per += __shfl_xor(per, off);
            }
            if (lr == 0) {
                int row = m0 + i * 16 + lk * 4 + r;
                el[row * NH + w] = pel;
                er[row * NH + w] = per;
            }
        }
    }
}

// Fused edge logits + softmax (no max-subtract: logits bounded) + weighted
// bf16-z gather + residual/elu. Wave per node.
// Phase 1: lane = head*16 + slot16. Phase 2: 32 lanes x ushort8; per 16-edge
// block: all shfls -> all 8 independent loads -> all FMAs (explicit MLP).
// OOB slots: w=0, s=0 (row-0 load is L1-broadcast, contributes exact +0).
__global__ __launch_bounds__(256) void attn_aggr_k(
        const ushort* __restrict__ zbf,
        const float* __restrict__ el, const float* __restrict__ er,
        const int* __restrict__ deg, const int* __restrict__ slots,
        const ushort* __restrict__ hin, ushort* __restrict__ hout,
        int residual) {
    int wid = threadIdx.x >> 6, lane = threadIdx.x & 63;
    int n = blockIdx.x * 4 + wid;
    int h = lane >> 4, j16 = lane & 15;
    int l32 = lane & 31, half = lane >> 5;
    int headL = l32 >> 3;             // head owning this lane's 8 cols
    int col8 = l32 * 8;
    int d = deg[n];
    if (d > SLOTS) d = SLOTS;
    const int* sl = slots + (size_t)n * SLOTS;
    float ern = er[n * NH + h];
    float acc[8] = {};

    if (d <= 64) {
        float pv[4];
        int   sv[4];
        #pragma unroll
        for (int u = 0; u < 4; u++) {
            int k = u * 16 + j16;
            if (k < d) {
                sv[u] = sl[k];
                pv[u] = __expf(lrelu_f(el[sv[u] * NH + h] + ern));
            } else {
                sv[u] = 0;
                pv[u] = 0.f;
            }
        }
        float ssum = pv[0] + pv[1] + pv[2] + pv[3];
        #pragma unroll
        for (int off = 1; off < 16; off <<= 1) ssum += __shfl_xor(ssum, off);
        float rinv = 1.f / ssum;
        #pragma unroll
        for (int u = 0; u < 4; u++) pv[u] *= rinv;
        // phase 2: per 16-edge block, 3 explicit passes for max loads-in-flight.
        #pragma unroll
        for (int u = 0; u < 4; u++) {
            if (u * 16 >= d) break;
            float w8[8];
            int   s8[8];
            #pragma unroll
            for (int jj = 0; jj < 8; jj++) {
                int srcl = headL * 16 + jj * 2 + half;
                w8[jj] = __shfl(pv[u], srcl);
                s8[jj] = __shfl(sv[u], srcl);
            }
            ushort8v zv8[8];
            #pragma unroll
            for (int jj = 0; jj < 8; jj++)
                zv8[jj] = *reinterpret_cast<const ushort8v*>(&zbf[(size_t)s8[jj] * HD + col8]);
            #pragma unroll
            for (int jj = 0; jj < 8; jj++)
                #pragma unroll
                for (int t = 0; t < 8; t++) acc[t] += bf2f(zv8[jj][t]) * w8[jj];
        }
        // combine the two halves' partial sums (each took alternating edges)
        #pragma unroll
        for (int t = 0; t < 8; t++) acc[t] += __shfl_xor(acc[t], 32);
    } else {
        // 64 < d <= SLOTS fallback (essentially never hit); full sum per lane.
        float ssum = 0.f;
        for (int k = j16; k < d; k += 16)
            ssum += __expf(lrelu_f(el[sl[k] * NH + h] + ern));
        #pragma unroll
        for (int off = 1; off < 16; off <<= 1) ssum += __shfl_xor(ssum, off);
        float rinv = 1.f / ssum;
        float rinvL = __shfl(rinv, headL * 16);
        float ernL = er[n * NH + headL];
        for (int k = 0; k < d; k++) {
            int s = sl[k];
            float w = __expf(lrelu_f(el[s * NH + headL] + ernL)) * rinvL;
            ushort8v zv = *reinterpret_cast<const ushort8v*>(&zbf[(size_t)s * HD + col8]);
            #pragma unroll
            for (int t = 0; t < 8; t++) acc[t] += bf2f(zv[t]) * w;
        }
    }

    if (half == 0) {
        size_t o = (size_t)n * HD + col8;
        ushort8v r;
        if (residual) {
            ushort8v hv = *reinterpret_cast<const ushort8v*>(&hin[o]);
            #pragma unroll
            for (int t = 0; t < 8; t++)
                r[t] = f2bf(elu_f(elu_f(acc[t] + bf2f(hv[t]))));
        } else {
            #pragma unroll
            for (int t = 0; t < 8; t++)
                r[t] = f2bf(elu_f(acc[t]));
        }
        *reinterpret_cast<ushort8v*>(&hout[o]) = r;
    }
}

// per-graph mean (4-way node split over 1024 threads) + elu + classifier.
__global__ __launch_bounds__(1024) void poolcls_k(const ushort* __restrict__ h,
                                                  const float* __restrict__ Wc,
                                                  const float* __restrict__ bc,
                                                  float* __restrict__ out) {
    __shared__ float part[4][HD];
    __shared__ float hv[HD];
    int g = blockIdx.x, t = threadIdx.x;
    int col = t & 255, q = t >> 8;               // quarter 0..3
    const ushort* p = h + (size_t)g * NPG * HD + (size_t)q * (NPG / 4) * HD + col;
    float s = 0.f;
    for (int i = 0; i < NPG / 4; i++) s += bf2f(p[(size_t)i * HD]);
    part[q][col] = s;
    __syncthreads();
    if (t < HD) {
        float tot = part[0][t] + part[1][t] + part[2][t] + part[3][t];
        hv[t] = elu_f(tot * (1.0f / NPG));
    }
    __syncthreads();
    if (t < NCLS) {
        float acc = bc[t];
        for (int k = 0; k < HD; k++) acc += hv[k] * Wc[k * NCLS + t];
        out[g * NCLS + t] = acc;
    }
}

extern "C" void kernel_launch(void* const* d_in, const int* in_sizes, int n_in,
                              void* d_out, int out_size, void* d_ws, size_t ws_size,
                              hipStream_t stream) {
    const float* x   = (const float*)d_in[0];
    const int*   src = (const int*)d_in[1];
    const int*   dst = (const int*)d_in[2];
    const float* W0  = (const float*)d_in[4];
    const float* al0 = (const float*)d_in[5];
    const float* ar0 = (const float*)d_in[6];
    const float* W1  = (const float*)d_in[7];
    const float* al1 = (const float*)d_in[8];
    const float* ar1 = (const float*)d_in[9];
    const float* W2  = (const float*)d_in[10];
    const float* al2 = (const float*)d_in[11];
    const float* ar2 = (const float*)d_in[12];
    const float* Wc  = (const float*)d_in[13];
    const float* bc  = (const float*)d_in[14];
    float* out = (float*)d_out;

    char* ws = (char*)d_ws;
    size_t off = 0;
    auto alloc = [&](size_t bytes) -> void* {
        void* p = ws + off;
        off = (off + bytes + 255) & ~(size_t)255;
        return p;
    };
    ushort* hbuf     = (ushort*)alloc((size_t)NNODES * HD * 2);
    ushort* zbf      = (ushort*)alloc((size_t)NNODES * HD * 2);
    float*  el       = (float*)alloc((size_t)NNODES * NH * 4);
    float*  er       = (float*)alloc((size_t)NNODES * NH * 4);
    int*    deg      = (int*)alloc((size_t)NNODES * 4);
    int*    slots    = (int*)alloc((size_t)NNODES * SLOTS * 4);
    ushort* B0h      = (ushort*)alloc((size_t)128 * 256 * 2);
    ushort* B0l      = (ushort*)alloc((size_t)128 * 256 * 2);
    ushort* B1h      = (ushort*)alloc((size_t)256 * 256 * 2);
    ushort* B1l      = (ushort*)alloc((size_t)256 * 256 * 2);
    ushort* B2h      = (ushort*)alloc((size_t)256 * 256 * 2);
    ushort* B2l      = (ushort*)alloc((size_t)256 * 256 * 2);

    // ---- adjacency (fixed-slot) + weight panels, one launch ----
    hipMemsetAsync(deg, 0, (size_t)NNODES * 4, stream);
    prep_k<<<NEDGES / 256 + (128 + 256 + 256), 256, 0, stream>>>(
        src, dst, deg, slots,
        W0, B0h, B0l, W1, B1h, B1l, W2, B2h, B2l);

    // layer 0: A = x (f32, 3-pass split)
    gemm_mfma_k<0><<<NNODES / 32, 256, 0, stream>>>(x, B0h, B0l, al0, ar0,
                                                    zbf, el, er, 128);
    attn_aggr_k<<<NNODES / 4, 256, 0, stream>>>(zbf, el, er, deg, slots,
                                                nullptr, hbuf, 0);
    // layers 1-2: A = h (bf16, 2-pass)
    gemm_mfma_k<1><<<NNODES / 32, 256, 0, stream>>>(hbuf, B1h, B1l, al1, ar1,
                                                    zbf, el, er, 256);
    attn_aggr_k<<<NNODES / 4, 256, 0, stream>>>(zbf, el, er, deg, slots,
                                                hbuf, hbuf, 1);
    gemm_mfma_k<1><<<NNODES / 32, 256, 0, stream>>>(hbuf, B2h, B2l, al2, ar2,
                                                    zbf, el, er, 256);
    attn_aggr_k<<<NNODES / 4, 256, 0, stream>>>(zbf, el, er, deg, slots,
                                                hbuf, hbuf, 1);

    poolcls_k<<<NGRAPH, 1024, 0, stream>>>(hbuf, Wc, bc, out);
}

// Round 15
// 271.137 us; speedup vs baseline: 1.1619x; 1.0147x over previous
//
#include <hip/hip_runtime.h>

// GATPool: 3-layer GAT (N=20480, E=327680, H=4, D=64) + mean pool + classifier.
// R14: R13 + phase-2 weight/src broadcasts moved from ds_bpermute (__shfl) to
// bank-padded LDS staging (lw[wid][h][68], lsv[wid][68]) -> broadcast-class
// reads, no bpermute bank conflicts.

#define NNODES 20480
#define NEDGES 327680
#define NGRAPH 64
#define NPG    320        // nodes per graph
#define HD     256        // H*D
#define NH     4
#define NCLS   10
#define SLOTS  80         // max in-degree slack (true max ~40, P(>64)~1e-19)

typedef __attribute__((ext_vector_type(8))) short short8;
typedef __attribute__((ext_vector_type(8))) unsigned short ushort8v;
typedef __attribute__((ext_vector_type(4))) float f32x4;

__device__ __forceinline__ float elu_f(float x)   { return x > 0.f ? x : expm1f(x); }
__device__ __forceinline__ float lrelu_f(float x) { return x > 0.f ? x : 0.2f * x; }

__device__ __forceinline__ ushort f2bf(float v) {
    uint u = __float_as_uint(v);
    uint r = (u + 0x7fffu + ((u >> 16) & 1u)) >> 16;
    return (ushort)r;
}
__device__ __forceinline__ float bf2f(ushort u) {
    return __uint_as_float(((uint)u) << 16);
}

// truncation split of 8 consecutive f32 -> bf16 hi/lo fragments.
__device__ __forceinline__ void split8(const float* __restrict__ p,
                                       short8& hi, short8& lo) {
    float4 a = *reinterpret_cast<const float4*>(p);
    float4 b = *reinterpret_cast<const float4*>(p + 4);
    float v[8] = {a.x, a.y, a.z, a.w, b.x, b.y, b.z, b.w};
    #pragma unroll
    for (int e = 0; e < 8; e++) {
        uint u = __float_as_uint(v[e]);
        hi[e] = (short)(u >> 16);
        float hf = __uint_as_float(u & 0xFFFF0000u);
        float lf = v[e] - hf;                      // exact
        lo[e] = (short)(__float_as_uint(lf) >> 16);
    }
}

// Combined prep: blocks [0,1280) fill adjacency slots; rest split W0/W1/W2
// into bf16 hi/lo fragment panels.
__global__ __launch_bounds__(256) void prep_k(
        const int* __restrict__ src, const int* __restrict__ dst,
        int* __restrict__ deg, int* __restrict__ slots,
        const float* __restrict__ W0, ushort* __restrict__ B0h, ushort* __restrict__ B0l,
        const float* __restrict__ W1, ushort* __restrict__ B1h, ushort* __restrict__ B1l,
        const float* __restrict__ W2, ushort* __restrict__ B2h, ushort* __restrict__ B2l) {
    int b = blockIdx.x;
    if (b < NEDGES / 256) {
        int e = b * 256 + threadIdx.x;
        int d = dst[e];
        int pos = atomicAdd(&deg[d], 1);
        if (pos < SLOTS) slots[d * SLOTS + pos] = src[e];
    } else {
        int idx = (b - NEDGES / 256) * 256 + threadIdx.x;
        const float* W; ushort *Bh, *Bl;
        if (idx < 128 * 256)          { W = W0; Bh = B0h; Bl = B0l; }
        else if (idx < 384 * 256)     { W = W1; Bh = B1h; Bl = B1l; idx -= 128 * 256; }
        else                          { W = W2; Bh = B2h; Bl = B2l; idx -= 384 * 256; }
        int k = idx >> 8, col = idx & 255;
        float v = W[idx];
        ushort h = f2bf(v);
        float vh = bf2f(h);
        ushort l = f2bf(v - vh);
        size_t o = (size_t)(k >> 5) * 8192 + (size_t)col * 32 + (k & 31);
        Bh[o] = h;
        Bl[o] = l;
    }
}

// z = A*B via split-bf16 MFMA. ABF16=0: A f32, in-register split, 3 passes.
// ABF16=1: A bf16 rows, 2 passes (a_lo==0). Writes bf16 z + fused el/er.
template<int ABF16>
__global__ __launch_bounds__(256) void gemm_mfma_k(
        const void* __restrict__ Av,
        const ushort* __restrict__ Bhi, const ushort* __restrict__ Blo,
        const float* __restrict__ al_, const float* __restrict__ ar_,
        ushort* __restrict__ zbf, float* __restrict__ el, float* __restrict__ er,
        int K) {
    int m0 = blockIdx.x * 32;
    int w = threadIdx.x >> 6, l = threadIdx.x & 63;
    int n0 = w * 64;
    int lr = l & 15, lk = l >> 4;
    f32x4 acc[2][4] = {};
    int ksteps = K >> 5;
    for (int kt = 0; kt < ksteps; kt++) {
        int kbase = kt * 32 + lk * 8;
        short8 a_hi[2], a_lo[2], b_hi[4], b_lo[4];
        #pragma unroll
        for (int i = 0; i < 2; i++) {
            size_t off = (size_t)(m0 + i * 16 + lr) * K + kbase;
            if (ABF16) {
                a_hi[i] = *reinterpret_cast<const short8*>((const ushort*)Av + off);
            } else {
                split8((const float*)Av + off, a_hi[i], a_lo[i]);
            }
        }
        #pragma unroll
        for (int j = 0; j < 4; j++) {
            size_t off = (size_t)kt * 8192 + (size_t)(n0 + j * 16 + lr) * 32 + lk * 8;
            b_hi[j] = *reinterpret_cast<const short8*>(Bhi + off);
            b_lo[j] = *reinterpret_cast<const short8*>(Blo + off);
        }
        #pragma unroll
        for (int i = 0; i < 2; i++)
            #pragma unroll
            for (int j = 0; j < 4; j++) {
                acc[i][j] = __builtin_amdgcn_mfma_f32_16x16x32_bf16(a_hi[i], b_hi[j], acc[i][j], 0, 0, 0);
                acc[i][j] = __builtin_amdgcn_mfma_f32_16x16x32_bf16(a_hi[i], b_lo[j], acc[i][j], 0, 0, 0);
                if (!ABF16)
                    acc[i][j] = __builtin_amdgcn_mfma_f32_16x16x32_bf16(a_lo[i], b_hi[j], acc[i][j], 0, 0, 0);
            }
    }
    float alv[4], arv[4];
    #pragma unroll
    for (int j = 0; j < 4; j++) {
        int col = n0 + j * 16 + lr;
        alv[j] = al_[col];
        arv[j] = ar_[col];
    }
    #pragma unroll
    for (int i = 0; i < 2; i++) {
        #pragma unroll
        for (int r = 0; r < 4; r++) {
            float pel = 0.f, per = 0.f;
            #pragma unroll
            for (int j = 0; j < 4; j++) {
                float v = acc[i][j][r];
                pel += v * alv[j];
                per += v * arv[j];
                int row = m0 + i * 16 + lk * 4 + r;
                int col = n0 + j * 16 + lr;
                zbf[(size_t)row * HD + col] = f2bf(v);
            }
            #pragma unroll
            for (int off = 1; off < 16; off <<= 1) {
                pel += __shfl_xor(pel, off);
                per += __shfl_xor(per, off);
            }
            if (lr == 0) {
                int row = m0 + i * 16 + lk * 4 + r;
                el[row * NH + w] = pel;
                er[row * NH + w] = per;
            }
        }
    }
}

// Fused edge logits + softmax (no max-subtract: logits bounded) + weighted
// bf16-z gather + residual/elu. Wave per node.
// Phase 1: lane = head*16 + slot16; normalized weights staged to bank-padded
// LDS (lw[wid][h][68]) and src list (lsv[wid][68], head-independent).
// Phase 2: 32 lanes x ushort8; weights/srcs read from LDS (broadcast-class,
// 4-bank spread via the 68-pad), 8 independent loads per 16-edge block.
__global__ __launch_bounds__(256) void attn_aggr_k(
        const ushort* __restrict__ zbf,
        const float* __restrict__ el, const float* __restrict__ er,
        const int* __restrict__ deg, const int* __restrict__ slots,
        const ushort* __restrict__ hin, ushort* __restrict__ hout,
        int residual) {
    __shared__ float lw[4][NH][68];
    __shared__ int   lsv[4][68];
    int wid = threadIdx.x >> 6, lane = threadIdx.x & 63;
    int n = blockIdx.x * 4 + wid;
    int h = lane >> 4, j16 = lane & 15;
    int l32 = lane & 31, half = lane >> 5;
    int headL = l32 >> 3;             // head owning this lane's 8 cols
    int col8 = l32 * 8;
    int d = deg[n];
    if (d > SLOTS) d = SLOTS;
    const int* sl = slots + (size_t)n * SLOTS;
    float ern = er[n * NH + h];
    float acc[8] = {};
    int fast = (d <= 64);

    if (fast) {
        float pv[4];
        int   sv[4];
        #pragma unroll
        for (int u = 0; u < 4; u++) {
            int k = u * 16 + j16;
            if (k < d) {
                sv[u] = sl[k];
                pv[u] = __expf(lrelu_f(el[sv[u] * NH + h] + ern));
            } else {
                sv[u] = 0;
                pv[u] = 0.f;
            }
        }
        float ssum = pv[0] + pv[1] + pv[2] + pv[3];
        #pragma unroll
        for (int off = 1; off < 16; off <<= 1) ssum += __shfl_xor(ssum, off);
        float rinv = 1.f / ssum;
        // stage normalized weights + srcs to LDS
        #pragma unroll
        for (int u = 0; u < 4; u++) {
            lw[wid][h][u * 16 + j16] = pv[u] * rinv;
            if (h == 0) lsv[wid][u * 16 + j16] = sv[u];
        }
    }
    __syncthreads();

    if (fast) {
        // phase 2: per 16-edge block, w/s from LDS, 8 independent 16B loads.
        #pragma unroll
        for (int u = 0; u < 4; u++) {
            if (u * 16 >= d) break;
            float w8[8];
            int   s8[8];
            #pragma unroll
            for (int jj = 0; jj < 8; jj++) {
                int e = u * 16 + jj * 2 + half;
                w8[jj] = lw[wid][headL][e];
                s8[jj] = lsv[wid][e];
            }
            ushort8v zv8[8];
            #pragma unroll
            for (int jj = 0; jj < 8; jj++)
                zv8[jj] = *reinterpret_cast<const ushort8v*>(&zbf[(size_t)s8[jj] * HD + col8]);
            #pragma unroll
            for (int jj = 0; jj < 8; jj++)
                #pragma unroll
                for (int t = 0; t < 8; t++) acc[t] += bf2f(zv8[jj][t]) * w8[jj];
        }
        // combine the two halves' partial sums (each took alternating edges)
        #pragma unroll
        for (int t = 0; t < 8; t++) acc[t] += __shfl_xor(acc[t], 32);
    } else {
        // 64 < d <= SLOTS fallback (essentially never hit); full sum per lane.
        float ssum = 0.f;
        for (int k = j16; k < d; k += 16)
            ssum += __expf(lrelu_f(el[sl[k] * NH + h] + ern));
        #pragma unroll
        for (int off = 1; off < 16; off <<= 1) ssum += __shfl_xor(ssum, off);
        float rinv = 1.f / ssum;
        float rinvL = __shfl(rinv, headL * 16);
        float ernL = er[n * NH + headL];
        for (int k = 0; k < d; k++) {
            int s = sl[k];
            float w = __expf(lrelu_f(el[s * NH + headL] + ernL)) * rinvL;
            ushort8v zv = *reinterpret_cast<const ushort8v*>(&zbf[(size_t)s * HD + col8]);
            #pragma unroll
            for (int t = 0; t < 8; t++) acc[t] += bf2f(zv[t]) * w;
        }
    }

    if (half == 0) {
        size_t o = (size_t)n * HD + col8;
        ushort8v r;
        if (residual) {
            ushort8v hv = *reinterpret_cast<const ushort8v*>(&hin[o]);
            #pragma unroll
            for (int t = 0; t < 8; t++)
                r[t] = f2bf(elu_f(elu_f(acc[t] + bf2f(hv[t]))));
        } else {
            #pragma unroll
            for (int t = 0; t < 8; t++)
                r[t] = f2bf(elu_f(acc[t]));
        }
        *reinterpret_cast<ushort8v*>(&hout[o]) = r;
    }
}

// per-graph mean (4-way node split over 1024 threads) + elu + classifier.
__global__ __launch_bounds__(1024) void poolcls_k(const ushort* __restrict__ h,
                                                  const float* __restrict__ Wc,
                                                  const float* __restrict__ bc,
                                                  float* __restrict__ out) {
    __shared__ float part[4][HD];
    __shared__ float hv[HD];
    int g = blockIdx.x, t = threadIdx.x;
    int col = t & 255, q = t >> 8;               // quarter 0..3
    const ushort* p = h + (size_t)g * NPG * HD + (size_t)q * (NPG / 4) * HD + col;
    float s = 0.f;
    for (int i = 0; i < NPG / 4; i++) s += bf2f(p[(size_t)i * HD]);
    part[q][col] = s;
    __syncthreads();
    if (t < HD) {
        float tot = part[0][t] + part[1][t] + part[2][t] + part[3][t];
        hv[t] = elu_f(tot * (1.0f / NPG));
    }
    __syncthreads();
    if (t < NCLS) {
        float acc = bc[t];
        for (int k = 0; k < HD; k++) acc += hv[k] * Wc[k * NCLS + t];
        out[g * NCLS + t] = acc;
    }
}

extern "C" void kernel_launch(void* const* d_in, const int* in_sizes, int n_in,
                              void* d_out, int out_size, void* d_ws, size_t ws_size,
                              hipStream_t stream) {
    const float* x   = (const float*)d_in[0];
    const int*   src = (const int*)d_in[1];
    const int*   dst = (const int*)d_in[2];
    const float* W0  = (const float*)d_in[4];
    const float* al0 = (const float*)d_in[5];
    const float* ar0 = (const float*)d_in[6];
    const float* W1  = (const float*)d_in[7];
    const float* al1 = (const float*)d_in[8];
    const float* ar1 = (const float*)d_in[9];
    const float* W2  = (const float*)d_in[10];
    const float* al2 = (const float*)d_in[11];
    const float* ar2 = (const float*)d_in[12];
    const float* Wc  = (const float*)d_in[13];
    const float* bc  = (const float*)d_in[14];
    float* out = (float*)d_out;

    char* ws = (char*)d_ws;
    size_t off = 0;
    auto alloc = [&](size_t bytes) -> void* {
        void* p = ws + off;
        off = (off + bytes + 255) & ~(size_t)255;
        return p;
    };
    ushort* hbuf     = (ushort*)alloc((size_t)NNODES * HD * 2);
    ushort* zbf      = (ushort*)alloc((size_t)NNODES * HD * 2);
    float*  el       = (float*)alloc((size_t)NNODES * NH * 4);
    float*  er       = (float*)alloc((size_t)NNODES * NH * 4);
    int*    deg      = (int*)alloc((size_t)NNODES * 4);
    int*    slots    = (int*)alloc((size_t)NNODES * SLOTS * 4);
    ushort* B0h      = (ushort*)alloc((size_t)128 * 256 * 2);
    ushort* B0l      = (ushort*)alloc((size_t)128 * 256 * 2);
    ushort* B1h      = (ushort*)alloc((size_t)256 * 256 * 2);
    ushort* B1l      = (ushort*)alloc((size_t)256 * 256 * 2);
    ushort* B2h      = (ushort*)alloc((size_t)256 * 256 * 2);
    ushort* B2l      = (ushort*)alloc((size_t)256 * 256 * 2);

    // ---- adjacency (fixed-slot) + weight panels, one launch ----
    hipMemsetAsync(deg, 0, (size_t)NNODES * 4, stream);
    prep_k<<<NEDGES / 256 + (128 + 256 + 256), 256, 0, stream>>>(
        src, dst, deg, slots,
        W0, B0h, B0l, W1, B1h, B1l, W2, B2h, B2l);

    // layer 0: A = x (f32, 3-pass split)
    gemm_mfma_k<0><<<NNODES / 32, 256, 0, stream>>>(x, B0h, B0l, al0, ar0,
                                                    zbf, el, er, 128);
    attn_aggr_k<<<NNODES / 4, 256, 0, stream>>>(zbf, el, er, deg, slots,
                                                nullptr, hbuf, 0);
    // layers 1-2: A = h (bf16, 2-pass)
    gemm_mfma_k<1><<<NNODES / 32, 256, 0, stream>>>(hbuf, B1h, B1l, al1, ar1,
                                                    zbf, el, er, 256);
    attn_aggr_k<<<NNODES / 4, 256, 0, stream>>>(zbf, el, er, deg, slots,
                                                hbuf, hbuf, 1);
    gemm_mfma_k<1><<<NNODES / 32, 256, 0, stream>>>(hbuf, B2h, B2l, al2, ar2,
                                                    zbf, el, er, 256);
    attn_aggr_k<<<NNODES / 4, 256, 0, stream>>>(zbf, el, er, deg, slots,
                                                hbuf, hbuf, 1);

    poolcls_k<<<NGRAPH, 1024, 0, stream>>>(hbuf, Wc, bc, out);
}